// Round 1
// baseline (390.833 us; speedup 1.0000x reference)
//
#include <hip/hip_runtime.h>

#define KNODES 4096
#define SEQL 32
#define DM 128
#define DFF 512
#define NEDGE 65536
#define NETOT (NEDGE + KNODES)

typedef float f32x4 __attribute__((ext_vector_type(4)));
typedef short s16x8 __attribute__((ext_vector_type(8)));
typedef short s16x4 __attribute__((ext_vector_type(4)));

#define MFMA16(a, b, c) __builtin_amdgcn_mfma_f32_16x16x32_bf16(a, b, c, 0, 0, 0)

// packed-weight fragment table (frag = 512 shorts = 64 lanes x 16B):
//  qkv: f = tile*4+kt            tiles 0..23   (rows n0=tile*16 of qkv_w[384][128])
//  out: f = 96 + tile*4+kt       tiles 0..7
//  ff1: f = 128 + tile*4+kt      tiles 0..31
//  ff2: f = 256 + ntile*16+kt    ntiles 0..7, kt 0..15 (K=512)
//  gat: f = 384 + tile*4+kt      tiles 0..7
#define F_OUT 96
#define F_FF1 128
#define F_FF2 256
#define F_GAT 384
#define NFRAG 416

__device__ __forceinline__ short f2bf(float f) {
  union { float f; unsigned u; } v; v.f = f;
  unsigned r = (v.u + 0x7FFFu + ((v.u >> 16) & 1u)) >> 16;
  return (short)r;
}

// packed RNE f32->bf16 pair: low16 = bf16(a), high16 = bf16(b).
// Bit-identical to f2bf (both round-to-nearest-even, finite inputs).
__device__ __forceinline__ unsigned cvt_pk(float a, float b) {
  unsigned r;
  asm("v_cvt_pk_bf16_f32 %0, %1, %2" : "=v"(r) : "v"(a), "v"(b));
  return r;
}

__device__ __forceinline__ float gelu_exact(float v) {
  return 0.5f * v * (1.f + erff(v * 0.70710678118654752440f));
}

// LayerNorm one row-slice: 16 lanes per row, 8 elems per lane.
__device__ __forceinline__ void ln_to_bf16(const float* XF, short* AB,
                                           const float* __restrict__ g,
                                           const float* __restrict__ b,
                                           int r, int cb) {
  const float* xr = XF + r * 132 + cb;
  float v[8]; float s = 0.f, ss = 0.f;
#pragma unroll
  for (int i = 0; i < 8; ++i) { v[i] = xr[i]; s += v[i]; ss += v[i] * v[i]; }
  s += __shfl_xor(s, 1); ss += __shfl_xor(ss, 1);
  s += __shfl_xor(s, 2); ss += __shfl_xor(ss, 2);
  s += __shfl_xor(s, 4); ss += __shfl_xor(ss, 4);
  s += __shfl_xor(s, 8); ss += __shfl_xor(ss, 8);
  const float mean = s * (1.f / 128.f);
  const float var = ss * (1.f / 128.f) - mean * mean;
  const float rs = rsqrtf(var + 1e-5f);
  const float* gp = g + cb; const float* bp = b + cb;
  unsigned o[4];
#pragma unroll
  for (int i = 0; i < 4; ++i) {
    const float a0 = (v[2 * i] - mean) * rs * gp[2 * i] + bp[2 * i];
    const float a1 = (v[2 * i + 1] - mean) * rs * gp[2 * i + 1] + bp[2 * i + 1];
    o[i] = cvt_pk(a0, a1);
  }
  *(s16x8*)(AB + r * 136 + cb) = *(s16x8*)o;
}

// LDS map (bytes), total 53248:
//  XF @0 fp32[32][132]; AB/Sf/Pb @16896; Qb @25600; Kb @34304 (Fb aliases Qb+Kb);
//  Vt @43008 bf16[128][40].
__global__ __launch_bounds__(512, 4) void temporal_kernel(
    const float* __restrict__ x,
    const float* __restrict__ ln1_g, const float* __restrict__ ln1_b,
    const short* __restrict__ wpk, const float* __restrict__ qkv_b,
    const float* __restrict__ out_b,
    const float* __restrict__ ln2_g, const float* __restrict__ ln2_b,
    const float* __restrict__ ff1_b, const float* __restrict__ ff2_b,
    const float* __restrict__ att_src, const float* __restrict__ att_dst,
    short* __restrict__ h_out, float* __restrict__ as_out, float* __restrict__ ad_out) {
  __shared__ __align__(16) char smem[53248];
  float* XF = (float*)smem;
  short* AB = (short*)(smem + 16896);
  float* Sf = (float*)(smem + 16896);
  short* Pb = (short*)(smem + 21504);
  short* Qb = (short*)(smem + 25600);
  short* Kb = (short*)(smem + 34304);
  short* Fb = (short*)(smem + 25600);
  short* Vt = (short*)(smem + 43008);

  const int t = threadIdx.x;
  const int w = t >> 6;                 // 8 waves
  const int lane = t & 63;
  const int q = lane >> 4, c = lane & 15;
  const int n = blockIdx.x;
  const int r16 = t >> 4, cb8 = (t & 15) * 8;

#define WPK(f) ((const s16x8*)(wpk + (size_t)(f) * 512 + lane * 8))

  // ---- QKV weight loads issued immediately (independent of everything)
  s16x8 bwq[3][4];
#pragma unroll
  for (int ii = 0; ii < 3; ++ii)
#pragma unroll
    for (int kt = 0; kt < 4; ++kt)
      bwq[ii][kt] = *WPK((w * 3 + ii) * 4 + kt);

  // ---- load x -> XF (fp32)
  {
#pragma unroll
    for (int i = t; i < 1024; i += 512) {
      const int row = i >> 5, c4i = i & 31;
      *(float4*)(XF + row * 132 + c4i * 4) =
          *(const float4*)(x + (size_t)n * (SEQL * DM) + i * 4);
    }
  }
  __syncthreads();

  // ---- LN1 -> AB
  ln_to_bf16(XF, AB, ln1_g, ln1_b, r16, cb8);
  __syncthreads();

  // ---- QKV GEMM: 24 N-tiles, 3 per wave (weights preloaded).
  {
    s16x8 a[2][4];
#pragma unroll
    for (int mt = 0; mt < 2; ++mt)
#pragma unroll
      for (int kt = 0; kt < 4; ++kt)
        a[mt][kt] = *(const s16x8*)(AB + (mt * 16 + c) * 136 + kt * 32 + q * 8);
#pragma unroll
    for (int ii = 0; ii < 3; ++ii) {
      const int n0 = (w * 3 + ii) * 16;
      f32x4 acc0 = {0.f, 0.f, 0.f, 0.f}, acc1 = {0.f, 0.f, 0.f, 0.f};
#pragma unroll
      for (int kt = 0; kt < 4; ++kt) {
        acc0 = MFMA16(a[0][kt], bwq[ii][kt], acc0);
        acc1 = MFMA16(a[1][kt], bwq[ii][kt], acc1);
      }
      const float bias = qkv_b[n0 + c];
      const unsigned u0 = cvt_pk(acc0[0] + bias, acc0[1] + bias);
      const unsigned u1 = cvt_pk(acc0[2] + bias, acc0[3] + bias);
      const unsigned u2 = cvt_pk(acc1[0] + bias, acc1[1] + bias);
      const unsigned u3 = cvt_pk(acc1[2] + bias, acc1[3] + bias);
      if (n0 < 128) {            // Q
        Qb[(q * 4 + 0) * 136 + n0 + c] = (short)u0;
        Qb[(q * 4 + 1) * 136 + n0 + c] = (short)(u0 >> 16);
        Qb[(q * 4 + 2) * 136 + n0 + c] = (short)u1;
        Qb[(q * 4 + 3) * 136 + n0 + c] = (short)(u1 >> 16);
        Qb[(16 + q * 4 + 0) * 136 + n0 + c] = (short)u2;
        Qb[(16 + q * 4 + 1) * 136 + n0 + c] = (short)(u2 >> 16);
        Qb[(16 + q * 4 + 2) * 136 + n0 + c] = (short)u3;
        Qb[(16 + q * 4 + 3) * 136 + n0 + c] = (short)(u3 >> 16);
      } else if (n0 < 256) {     // K
        const int cc = n0 - 128 + c;
        Kb[(q * 4 + 0) * 136 + cc] = (short)u0;
        Kb[(q * 4 + 1) * 136 + cc] = (short)(u0 >> 16);
        Kb[(q * 4 + 2) * 136 + cc] = (short)u1;
        Kb[(q * 4 + 3) * 136 + cc] = (short)(u1 >> 16);
        Kb[(16 + q * 4 + 0) * 136 + cc] = (short)u2;
        Kb[(16 + q * 4 + 1) * 136 + cc] = (short)(u2 >> 16);
        Kb[(16 + q * 4 + 2) * 136 + cc] = (short)u3;
        Kb[(16 + q * 4 + 3) * 136 + cc] = (short)(u3 >> 16);
      } else {                   // V -> Vt transposed
        const int d = n0 - 256 + c;
        union { unsigned u[2]; s16x4 v; } pk0, pk1;
        pk0.u[0] = u0; pk0.u[1] = u1;
        pk1.u[0] = u2; pk1.u[1] = u3;
        *(s16x4*)(Vt + d * 40 + q * 4) = pk0.v;
        *(s16x4*)(Vt + d * 40 + 16 + q * 4) = pk1.v;
      }
    }
  }
  __syncthreads();

  // ---- scores S = Q K^T / sqrt(128). 4 tiles on waves 0-3.
  if (w < 4) {
    const int mt = w & 1, nt = w >> 1;
    s16x8 aq[4], bk[4];
#pragma unroll
    for (int kt = 0; kt < 4; ++kt) {
      aq[kt] = *(const s16x8*)(Qb + (mt * 16 + c) * 136 + kt * 32 + q * 8);
      bk[kt] = *(const s16x8*)(Kb + (nt * 16 + c) * 136 + kt * 32 + q * 8);
    }
    f32x4 acc = {0.f, 0.f, 0.f, 0.f};
#pragma unroll
    for (int kt = 0; kt < 4; ++kt) acc = MFMA16(aq[kt], bk[kt], acc);
#pragma unroll
    for (int i = 0; i < 4; ++i)
      Sf[(mt * 16 + q * 4 + i) * 36 + nt * 16 + c] = acc[i] * 0.08838834764831845f;
  }
  __syncthreads();

  // ---- softmax rows of Sf -> Pb (threads 0..255)
  if (t < 256) {
    const int r8 = t >> 3, c4 = (t & 7) * 4;
    float4 sv = *(const float4*)(Sf + r8 * 36 + c4);
    float mx = fmaxf(fmaxf(sv.x, sv.y), fmaxf(sv.z, sv.w));
    mx = fmaxf(mx, __shfl_xor(mx, 1));
    mx = fmaxf(mx, __shfl_xor(mx, 2));
    mx = fmaxf(mx, __shfl_xor(mx, 4));
    float e0 = expf(sv.x - mx), e1 = expf(sv.y - mx), e2 = expf(sv.z - mx), e3 = expf(sv.w - mx);
    float sum = e0 + e1 + e2 + e3;
    sum += __shfl_xor(sum, 1);
    sum += __shfl_xor(sum, 2);
    sum += __shfl_xor(sum, 4);
    const float inv = 1.f / sum;
    union { unsigned u[2]; s16x4 v; } pw;
    pw.u[0] = cvt_pk(e0 * inv, e1 * inv);
    pw.u[1] = cvt_pk(e2 * inv, e3 * inv);
    *(s16x4*)(Pb + r8 * 40 + c4) = pw.v;
  }
  __syncthreads();

  // ---- attn = P @ V (1 d-tile per wave) + early proj-weight loads
  s16x8 bwp[4];
  {
#pragma unroll
    for (int kt = 0; kt < 4; ++kt) bwp[kt] = *WPK(F_OUT + w * 4 + kt);
    s16x8 ap0 = *(const s16x8*)(Pb + c * 40 + q * 8);
    s16x8 ap1 = *(const s16x8*)(Pb + (16 + c) * 40 + q * 8);
    const int d0 = w * 16;
    s16x8 bv = *(const s16x8*)(Vt + (d0 + c) * 40 + q * 8);
    f32x4 acc0 = {0.f, 0.f, 0.f, 0.f}, acc1 = {0.f, 0.f, 0.f, 0.f};
    acc0 = MFMA16(ap0, bv, acc0);
    acc1 = MFMA16(ap1, bv, acc1);
    const unsigned u0 = cvt_pk(acc0[0], acc0[1]);
    const unsigned u1 = cvt_pk(acc0[2], acc0[3]);
    const unsigned u2 = cvt_pk(acc1[0], acc1[1]);
    const unsigned u3 = cvt_pk(acc1[2], acc1[3]);
    Qb[(q * 4 + 0) * 136 + d0 + c] = (short)u0;
    Qb[(q * 4 + 1) * 136 + d0 + c] = (short)(u0 >> 16);
    Qb[(q * 4 + 2) * 136 + d0 + c] = (short)u1;
    Qb[(q * 4 + 3) * 136 + d0 + c] = (short)(u1 >> 16);
    Qb[(16 + q * 4 + 0) * 136 + d0 + c] = (short)u2;
    Qb[(16 + q * 4 + 1) * 136 + d0 + c] = (short)(u2 >> 16);
    Qb[(16 + q * 4 + 2) * 136 + d0 + c] = (short)u3;
    Qb[(16 + q * 4 + 3) * 136 + d0 + c] = (short)(u3 >> 16);
  }
  __syncthreads();

  // ---- proj: XF += attn @ out_w^T + out_b (weights preloaded)
  {
    s16x8 aa[2][4];
#pragma unroll
    for (int mt = 0; mt < 2; ++mt)
#pragma unroll
      for (int kt = 0; kt < 4; ++kt)
        aa[mt][kt] = *(const s16x8*)(Qb + (mt * 16 + c) * 136 + kt * 32 + q * 8);
    const int n0 = w * 16;
    f32x4 acc0 = {0.f, 0.f, 0.f, 0.f}, acc1 = {0.f, 0.f, 0.f, 0.f};
#pragma unroll
    for (int kt = 0; kt < 4; ++kt) {
      acc0 = MFMA16(aa[0][kt], bwp[kt], acc0);
      acc1 = MFMA16(aa[1][kt], bwp[kt], acc1);
    }
    const float bias = out_b[n0 + c];
#pragma unroll
    for (int i = 0; i < 4; ++i) {
      XF[(q * 4 + i) * 132 + n0 + c] += acc0[i] + bias;
      XF[(16 + q * 4 + i) * 132 + n0 + c] += acc1[i] + bias;
    }
  }
  __syncthreads();

  // ---- LN2 -> AB
  ln_to_bf16(XF, AB, ln2_g, ln2_b, r16, cb8);
  __syncthreads();

  // ---- FFN: two 256-col chunks; all weight frags hoisted per chunk.
  {
    s16x8 af[2][4];
#pragma unroll
    for (int mt = 0; mt < 2; ++mt)
#pragma unroll
      for (int kt = 0; kt < 4; ++kt)
        af[mt][kt] = *(const s16x8*)(AB + (mt * 16 + c) * 136 + kt * 32 + q * 8);
    f32x4 facc0 = {0.f, 0.f, 0.f, 0.f}, facc1 = {0.f, 0.f, 0.f, 0.f};

    for (int ch = 0; ch < 2; ++ch) {
      s16x8 bw1[2][4], bw2[8];
#pragma unroll
      for (int ii = 0; ii < 2; ++ii)
#pragma unroll
        for (int kt = 0; kt < 4; ++kt)
          bw1[ii][kt] = *WPK(F_FF1 + (ch * 16 + w * 2 + ii) * 4 + kt);
#pragma unroll
      for (int kt = 0; kt < 8; ++kt)
        bw2[kt] = *WPK(F_FF2 + w * 16 + ch * 8 + kt);

#pragma unroll
      for (int ii = 0; ii < 2; ++ii) {
        const int ntl = w * 2 + ii;
        const int n0g = ch * 256 + ntl * 16;
        f32x4 acc0 = {0.f, 0.f, 0.f, 0.f}, acc1 = {0.f, 0.f, 0.f, 0.f};
#pragma unroll
        for (int kt = 0; kt < 4; ++kt) {
          acc0 = MFMA16(af[0][kt], bw1[ii][kt], acc0);
          acc1 = MFMA16(af[1][kt], bw1[ii][kt], acc1);
        }
        const float bias = ff1_b[n0g + c];
        const unsigned g0 = cvt_pk(gelu_exact(acc0[0] + bias), gelu_exact(acc0[1] + bias));
        const unsigned g1 = cvt_pk(gelu_exact(acc0[2] + bias), gelu_exact(acc0[3] + bias));
        const unsigned g2 = cvt_pk(gelu_exact(acc1[0] + bias), gelu_exact(acc1[1] + bias));
        const unsigned g3 = cvt_pk(gelu_exact(acc1[2] + bias), gelu_exact(acc1[3] + bias));
        Fb[(q * 4 + 0) * 264 + ntl * 16 + c] = (short)g0;
        Fb[(q * 4 + 1) * 264 + ntl * 16 + c] = (short)(g0 >> 16);
        Fb[(q * 4 + 2) * 264 + ntl * 16 + c] = (short)g1;
        Fb[(q * 4 + 3) * 264 + ntl * 16 + c] = (short)(g1 >> 16);
        Fb[(16 + q * 4 + 0) * 264 + ntl * 16 + c] = (short)g2;
        Fb[(16 + q * 4 + 1) * 264 + ntl * 16 + c] = (short)(g2 >> 16);
        Fb[(16 + q * 4 + 2) * 264 + ntl * 16 + c] = (short)g3;
        Fb[(16 + q * 4 + 3) * 264 + ntl * 16 + c] = (short)(g3 >> 16);
      }
      __syncthreads();
#pragma unroll
      for (int kt = 0; kt < 8; ++kt) {
        s16x8 a0 = *(const s16x8*)(Fb + c * 264 + kt * 32 + q * 8);
        s16x8 a1 = *(const s16x8*)(Fb + (16 + c) * 264 + kt * 32 + q * 8);
        facc0 = MFMA16(a0, bw2[kt], facc0);
        facc1 = MFMA16(a1, bw2[kt], facc1);
      }
      __syncthreads();
    }
    // epilogue fused with xt->bf16: AB = bf16(XF + facc + ff2_b)
    {
      const int n0 = w * 16;
      const float bias = ff2_b[n0 + c];
      const float a0 = XF[(q * 4 + 0) * 132 + n0 + c] + facc0[0] + bias;
      const float a1 = XF[(q * 4 + 1) * 132 + n0 + c] + facc0[1] + bias;
      const float a2 = XF[(q * 4 + 2) * 132 + n0 + c] + facc0[2] + bias;
      const float a3 = XF[(q * 4 + 3) * 132 + n0 + c] + facc0[3] + bias;
      const float b0 = XF[(16 + q * 4 + 0) * 132 + n0 + c] + facc1[0] + bias;
      const float b1 = XF[(16 + q * 4 + 1) * 132 + n0 + c] + facc1[1] + bias;
      const float b2 = XF[(16 + q * 4 + 2) * 132 + n0 + c] + facc1[2] + bias;
      const float b3 = XF[(16 + q * 4 + 3) * 132 + n0 + c] + facc1[3] + bias;
      const unsigned u0 = cvt_pk(a0, a1);
      const unsigned u1 = cvt_pk(a2, a3);
      const unsigned u2 = cvt_pk(b0, b1);
      const unsigned u3 = cvt_pk(b2, b3);
      AB[(q * 4 + 0) * 136 + n0 + c] = (short)u0;
      AB[(q * 4 + 1) * 136 + n0 + c] = (short)(u0 >> 16);
      AB[(q * 4 + 2) * 136 + n0 + c] = (short)u1;
      AB[(q * 4 + 3) * 136 + n0 + c] = (short)(u1 >> 16);
      AB[(16 + q * 4 + 0) * 136 + n0 + c] = (short)u2;
      AB[(16 + q * 4 + 1) * 136 + n0 + c] = (short)(u2 >> 16);
      AB[(16 + q * 4 + 2) * 136 + n0 + c] = (short)u3;
      AB[(16 + q * 4 + 3) * 136 + n0 + c] = (short)(u3 >> 16);
    }
  }
  // early GAT weight loads (independent of the barrier below)
  s16x8 bwg[4];
#pragma unroll
  for (int kt = 0; kt < 4; ++kt) bwg[kt] = *WPK(F_GAT + w * 4 + kt);
  __syncthreads();

  // ---- GAT projection h = xt @ gat_w^T -> XF (fp32); h_out written coalesced below
  {
    s16x8 ag[2][4];
#pragma unroll
    for (int mt = 0; mt < 2; ++mt)
#pragma unroll
      for (int kt = 0; kt < 4; ++kt)
        ag[mt][kt] = *(const s16x8*)(AB + (mt * 16 + c) * 136 + kt * 32 + q * 8);
    const int n0 = w * 16;
    f32x4 acc0 = {0.f, 0.f, 0.f, 0.f}, acc1 = {0.f, 0.f, 0.f, 0.f};
#pragma unroll
    for (int kt = 0; kt < 4; ++kt) {
      acc0 = MFMA16(ag[0][kt], bwg[kt], acc0);
      acc1 = MFMA16(ag[1][kt], bwg[kt], acc1);
    }
#pragma unroll
    for (int i = 0; i < 4; ++i) {
      const int r0 = q * 4 + i, r1 = 16 + q * 4 + i;
      XF[r0 * 132 + n0 + c] = acc0[i];
      XF[r1 * 132 + n0 + c] = acc1[i];
    }
  }
  __syncthreads();

  // ---- h_out: coalesced bf16 write (full 128B lines), 16B per thread
  {
    const int row = t >> 4;
    const float* xr = XF + row * 132 + cb8;
    unsigned o[4];
#pragma unroll
    for (int i = 0; i < 4; ++i) o[i] = cvt_pk(xr[2 * i], xr[2 * i + 1]);
    *(s16x8*)(h_out + ((size_t)n * SEQL + row) * DM + cb8) = *(s16x8*)o;
  }

  // ---- a_s / a_d
  if (t < 64) {
    const int row = t & 31;
    const float* vec = (t < 32) ? att_src : att_dst;
    const float* hr = XF + row * 132;
    float s = 0.f;
#pragma unroll
    for (int d = 0; d < DM; d += 4)
      s += hr[d] * vec[d] + hr[d + 1] * vec[d + 1] + hr[d + 2] * vec[d + 2] + hr[d + 3] * vec[d + 3];
    if (t < 32) as_out[n * SEQL + row] = s;
    else        ad_out[n * SEQL + row] = s;
  }
}

// fp32 -> bf16 tile-packed weight conversion: wpk[frag][lane][8].
__global__ void cvt_weights(const float* __restrict__ qkv_w, const float* __restrict__ out_w,
                            const float* __restrict__ ff1_w, const float* __restrict__ ff2_w,
                            const float* __restrict__ gat_w, short* __restrict__ wpk) {
  const int u = blockIdx.x * 256 + threadIdx.x;
  if (u >= NFRAG * 64) return;
  const int f = u >> 6, lane = u & 63;
  const int q = lane >> 4, c = lane & 15;
  const float* src; int row, kt, ld;
  if (f < F_OUT)       { src = qkv_w; ld = 128; int g = f;         row = (g >> 2) * 16 + c; kt = g & 3; }
  else if (f < F_FF1)  { src = out_w; ld = 128; int g = f - F_OUT; row = (g >> 2) * 16 + c; kt = g & 3; }
  else if (f < F_FF2)  { src = ff1_w; ld = 128; int g = f - F_FF1; row = (g >> 2) * 16 + c; kt = g & 3; }
  else if (f < F_GAT)  { src = ff2_w; ld = 512; int g = f - F_FF2; row = (g >> 4) * 16 + c; kt = g & 15; }
  else                 { src = gat_w; ld = 128; int g = f - F_GAT; row = (g >> 2) * 16 + c; kt = g & 3; }
  const float* p = src + row * ld + kt * 32 + q * 8;
  const float4 v0 = *(const float4*)p;
  const float4 v1 = *(const float4*)(p + 4);
  s16x8 o;
  o[0] = f2bf(v0.x); o[1] = f2bf(v0.y); o[2] = f2bf(v0.z); o[3] = f2bf(v0.w);
  o[4] = f2bf(v1.x); o[5] = f2bf(v1.y); o[6] = f2bf(v1.z); o[7] = f2bf(v1.w);
  *(s16x8*)(wpk + (size_t)f * 512 + lane * 8) = o;
}

__global__ void zero_counts(int* counts) {
  int i = blockIdx.x * 256 + threadIdx.x;
  if (i < KNODES) counts[i] = 0;
}

__global__ void hist_kernel(const int* __restrict__ ei, int* counts) {
  int i = blockIdx.x * 256 + threadIdx.x;
  if (i < NETOT) {
    int dst = (i < NEDGE) ? ei[NEDGE + i] : (i - NEDGE);
    atomicAdd(&counts[dst], 1);
  }
}

__global__ void scan_kernel(const int* __restrict__ counts, int* offs, int* cursor) {
  __shared__ int tmp[1024];
  const int t = threadIdx.x;
  const int base = t * 4;
  int c0 = counts[base], c1 = counts[base + 1], c2 = counts[base + 2], c3 = counts[base + 3];
  const int s = c0 + c1 + c2 + c3;
  tmp[t] = s;
  __syncthreads();
  for (int off = 1; off < 1024; off <<= 1) {
    int v = (t >= off) ? tmp[t - off] : 0;
    __syncthreads();
    tmp[t] += v;
    __syncthreads();
  }
  int o = tmp[t] - s;
  offs[base] = o; cursor[base] = o; o += c0;
  offs[base + 1] = o; cursor[base + 1] = o; o += c1;
  offs[base + 2] = o; cursor[base + 2] = o; o += c2;
  offs[base + 3] = o; cursor[base + 3] = o; o += c3;
  if (t == 1023) offs[KNODES] = o;
}

__global__ void scatter_kernel(const int* __restrict__ ei, int* cursor, int* __restrict__ csr) {
  int i = blockIdx.x * 256 + threadIdx.x;
  if (i < NETOT) {
    int src, dst;
    if (i < NEDGE) { src = ei[i]; dst = ei[NEDGE + i]; }
    else           { src = dst = i - NEDGE; }
    int pos = atomicAdd(&cursor[dst], 1);
    csr[pos] = src;
  }
}

// GAT aggregation: grid (KNODES, 2); single pass, deferred norm, prefetch-2.
#define ECH 32
__global__ __launch_bounds__(256) void gat_aggregate(
    const short* __restrict__ h, const float* __restrict__ as_g, const float* __restrict__ ad_g,
    const int* __restrict__ offs, const int* __restrict__ csr,
    const float* __restrict__ gat_b, float* __restrict__ out) {
  __shared__ float ad_s[16];
  __shared__ float ew[ECH * 17];
  __shared__ int   srcs[ECH];
  __shared__ float dred[16 * 33];
  __shared__ float invd[16];

  const int t = threadIdx.x;
  const int n = blockIdx.x;
  const int l0 = blockIdx.y * 16;
  if (t < 16) ad_s[t] = ad_g[n * SEQL + l0 + t];
  __syncthreads();
  const int beg = offs[n], end = offs[n + 1];

  const int s = t >> 3, lq = t & 7;
  float dpart0 = 0.f, dpart1 = 0.f;

  const int lane2 = t & 63;
  const int lg = t >> 6;
  const size_t roff = (size_t)(l0 + lg * 4) * DM + lane2 * 2;
  float acc[4][2];
#pragma unroll
  for (int j = 0; j < 4; ++j) { acc[j][0] = 0.f; acc[j][1] = 0.f; }

  for (int cb = beg; cb < end; cb += ECH) {
    const int cnt = min(ECH, end - cb);
    if (s < cnt) {
      const int src = csr[cb + s];
      if (lq == 0) srcs[s] = src;
      const float2 av = *(const float2*)(as_g + src * SEQL + l0 + lq * 2);
      float v0 = av.x + ad_s[lq * 2];
      v0 = v0 > 0.f ? v0 : 0.2f * v0;
      const float e0 = __expf(v0);
      float v1 = av.y + ad_s[lq * 2 + 1];
      v1 = v1 > 0.f ? v1 : 0.2f * v1;
      const float e1 = __expf(v1);
      ew[s * 17 + lq * 2] = e0;
      ew[s * 17 + lq * 2 + 1] = e1;
      dpart0 += e0; dpart1 += e1;
    }
    __syncthreads();
    // 2-deep software pipeline over the edge gather (FP order unchanged: ss ascending)
    unsigned curA[4], curB[4];
    {
      const short* hr = h + (size_t)srcs[0] * (SEQL * DM) + roff;
#pragma unroll
      for (int j = 0; j < 4; ++j) curA[j] = *(const unsigned*)(hr + j * DM);
    }
    if (cnt > 1) {
      const short* hr = h + (size_t)srcs[1] * (SEQL * DM) + roff;
#pragma unroll
      for (int j = 0; j < 4; ++j) curB[j] = *(const unsigned*)(hr + j * DM);
    }
    for (int ss = 0; ss < cnt; ss += 2) {
      unsigned nA[4], nB[4];
      if (ss + 2 < cnt) {
        const short* hr = h + (size_t)srcs[ss + 2] * (SEQL * DM) + roff;
#pragma unroll
        for (int j = 0; j < 4; ++j) nA[j] = *(const unsigned*)(hr + j * DM);
      }
      if (ss + 3 < cnt) {
        const short* hr = h + (size_t)srcs[ss + 3] * (SEQL * DM) + roff;
#pragma unroll
        for (int j = 0; j < 4; ++j) nB[j] = *(const unsigned*)(hr + j * DM);
      }
      {
        const float* ewp = ew + ss * 17 + lg * 4;
#pragma unroll
        for (int j = 0; j < 4; ++j) {
          const float h0 = __uint_as_float(curA[j] << 16);
          const float h1 = __uint_as_float(curA[j] & 0xFFFF0000u);
          const float wgt = ewp[j];
          acc[j][0] += wgt * h0;
          acc[j][1] += wgt * h1;
        }
      }
      if (ss + 1 < cnt) {
        const float* ewp = ew + (ss + 1) * 17 + lg * 4;
#pragma unroll
        for (int j = 0; j < 4; ++j) {
          const float h0 = __uint_as_float(curB[j] << 16);
          const float h1 = __uint_as_float(curB[j] & 0xFFFF0000u);
          const float wgt = ewp[j];
          acc[j][0] += wgt * h0;
          acc[j][1] += wgt * h1;
        }
      }
#pragma unroll
      for (int j = 0; j < 4; ++j) { curA[j] = nA[j]; curB[j] = nB[j]; }
    }
    __syncthreads();
  }

  dred[(lq * 2) * 33 + s] = dpart0;
  dred[(lq * 2 + 1) * 33 + s] = dpart1;
  __syncthreads();
  if (t < 16) {
    float sum = 0.f;
#pragma unroll
    for (int s2 = 0; s2 < 32; ++s2) sum += dred[t * 33 + s2];
    invd[t] = 1.f / (sum + 1e-16f);
  }
  __syncthreads();

  const float b0 = gat_b[lane2 * 2], b1 = gat_b[lane2 * 2 + 1];
#pragma unroll
  for (int j = 0; j < 4; ++j) {
    const int l = l0 + lg * 4 + j;
    const float iv = invd[lg * 4 + j];
    float2 o;
    o.x = acc[j][0] * iv + b0;
    o.y = acc[j][1] * iv + b1;
    *(float2*)(out + (size_t)n * (SEQL * DM) + l * DM + lane2 * 2) = o;
  }
}

extern "C" void kernel_launch(void* const* d_in, const int* in_sizes, int n_in,
                              void* d_out, int out_size, void* d_ws, size_t ws_size,
                              hipStream_t stream) {
  const float* x       = (const float*)d_in[0];
  const int* ei        = (const int*)d_in[1];
  const float* ln1_g   = (const float*)d_in[2];
  const float* ln1_b   = (const float*)d_in[3];
  const float* qkv_w   = (const float*)d_in[4];
  const float* qkv_b   = (const float*)d_in[5];
  const float* out_w   = (const float*)d_in[6];
  const float* out_b   = (const float*)d_in[7];
  const float* ln2_g   = (const float*)d_in[8];
  const float* ln2_b   = (const float*)d_in[9];
  const float* ff1_w   = (const float*)d_in[10];
  const float* ff1_b   = (const float*)d_in[11];
  const float* ff2_w   = (const float*)d_in[12];
  const float* ff2_b   = (const float*)d_in[13];
  const float* gat_w   = (const float*)d_in[14];
  const float* att_src = (const float*)d_in[15];
  const float* att_dst = (const float*)d_in[16];
  const float* gat_b   = (const float*)d_in[17];
  float* out = (float*)d_out;

  short* h    = (short*)d_ws;                             // 16777216 shorts (bf16)
  float* as_g = (float*)(h + (size_t)KNODES * SEQL * DM); // 131072 floats
  float* ad_g = as_g + KNODES * SEQL;                     // 131072
  int* counts = (int*)(ad_g + KNODES * SEQL);             // 4096
  int* offs   = counts + KNODES;                          // 4097
  int* cursor = offs + KNODES + 1;                        // 4096
  int* csr    = cursor + KNODES;                          // 69632
  size_t wofs = (size_t)((char*)(csr + NETOT) - (char*)d_ws);
  wofs = (wofs + 1023) & ~(size_t)1023;
  short* wpk = (short*)((char*)d_ws + wofs);              // 416*512 shorts

  cvt_weights<<<(NFRAG * 64 + 255) / 256, 256, 0, stream>>>(qkv_w, out_w, ff1_w, ff2_w, gat_w, wpk);
  zero_counts<<<(KNODES + 255) / 256, 256, 0, stream>>>(counts);
  hist_kernel<<<(NETOT + 255) / 256, 256, 0, stream>>>(ei, counts);
  scan_kernel<<<1, 1024, 0, stream>>>(counts, offs, cursor);
  scatter_kernel<<<(NETOT + 255) / 256, 256, 0, stream>>>(ei, cursor, csr);
  temporal_kernel<<<KNODES, 512, 0, stream>>>(
      x, ln1_g, ln1_b, wpk, qkv_b, out_b, ln2_g, ln2_b,
      ff1_b, ff2_b, att_src, att_dst, h, as_g, ad_g);
  gat_aggregate<<<dim3(KNODES, 2), 256, 0, stream>>>(h, as_g, ad_g, offs, csr, gat_b, out);
}

// Round 2
// 357.482 us; speedup vs baseline: 1.0933x; 1.0933x over previous
//
#include <hip/hip_runtime.h>

#define KNODES 4096
#define SEQL 32
#define DM 128
#define DFF 512
#define NEDGE 65536
#define NETOT (NEDGE + KNODES)

typedef float f32x4 __attribute__((ext_vector_type(4)));
typedef short s16x8 __attribute__((ext_vector_type(8)));
typedef short s16x4 __attribute__((ext_vector_type(4)));

#define MFMA16(a, b, c) __builtin_amdgcn_mfma_f32_16x16x32_bf16(a, b, c, 0, 0, 0)

// packed-weight fragment table (frag = 512 shorts = 64 lanes x 16B):
//  qkv: f = tile*4+kt            tiles 0..23   (rows n0=tile*16 of qkv_w[384][128])
//  out: f = 96 + tile*4+kt       tiles 0..7
//  ff1: f = 128 + tile*4+kt      tiles 0..31
//  ff2: f = 256 + ntile*16+kt    ntiles 0..7, kt 0..15 (K=512)
//  gat: f = 384 + tile*4+kt      tiles 0..7
#define F_OUT 96
#define F_FF1 128
#define F_FF2 256
#define F_GAT 384
#define NFRAG 416

__device__ __forceinline__ short f2bf(float f) {
  union { float f; unsigned u; } v; v.f = f;
  unsigned r = (v.u + 0x7FFFu + ((v.u >> 16) & 1u)) >> 16;
  return (short)r;
}

__device__ __forceinline__ float gelu_exact(float v) {
  return 0.5f * v * (1.f + erff(v * 0.70710678118654752440f));
}

// LayerNorm one row-slice: 16 lanes per row, 8 elems per lane.
__device__ __forceinline__ void ln_to_bf16(const float* XF, short* AB,
                                           const float* __restrict__ g,
                                           const float* __restrict__ b,
                                           int r, int cb) {
  const float* xr = XF + r * 132 + cb;
  float v[8]; float s = 0.f, ss = 0.f;
#pragma unroll
  for (int i = 0; i < 8; ++i) { v[i] = xr[i]; s += v[i]; ss += v[i] * v[i]; }
  s += __shfl_xor(s, 1); ss += __shfl_xor(ss, 1);
  s += __shfl_xor(s, 2); ss += __shfl_xor(ss, 2);
  s += __shfl_xor(s, 4); ss += __shfl_xor(ss, 4);
  s += __shfl_xor(s, 8); ss += __shfl_xor(ss, 8);
  const float mean = s * (1.f / 128.f);
  const float var = ss * (1.f / 128.f) - mean * mean;
  const float rs = rsqrtf(var + 1e-5f);
  const float* gp = g + cb; const float* bp = b + cb;
  short o[8];
#pragma unroll
  for (int i = 0; i < 8; ++i) o[i] = f2bf((v[i] - mean) * rs * gp[i] + bp[i]);
  *(s16x8*)(AB + r * 136 + cb) = *(s16x8*)o;
}

// LDS map (bytes), total 53248:
//  XF @0 fp32[32][132]; AB/Sf/Pb @16896; Qb @25600; Kb @34304 (Fb aliases Qb+Kb);
//  Vt @43008 bf16[128][40].
__global__ __launch_bounds__(512, 4) void temporal_kernel(
    const float* __restrict__ x,
    const float* __restrict__ ln1_g, const float* __restrict__ ln1_b,
    const short* __restrict__ wpk, const float* __restrict__ qkv_b,
    const float* __restrict__ out_b,
    const float* __restrict__ ln2_g, const float* __restrict__ ln2_b,
    const float* __restrict__ ff1_b, const float* __restrict__ ff2_b,
    const float* __restrict__ att_src, const float* __restrict__ att_dst,
    short* __restrict__ h_out, float* __restrict__ as_out, float* __restrict__ ad_out) {
  __shared__ __align__(16) char smem[53248];
  float* XF = (float*)smem;
  short* AB = (short*)(smem + 16896);
  float* Sf = (float*)(smem + 16896);
  short* Pb = (short*)(smem + 21504);
  short* Qb = (short*)(smem + 25600);
  short* Kb = (short*)(smem + 34304);
  short* Fb = (short*)(smem + 25600);
  short* Vt = (short*)(smem + 43008);

  const int t = threadIdx.x;
  const int w = t >> 6;                 // 8 waves
  const int lane = t & 63;
  const int q = lane >> 4, c = lane & 15;
  const int n = blockIdx.x;
  const int r16 = t >> 4, cb8 = (t & 15) * 8;

#define WPK(f) ((const s16x8*)(wpk + (size_t)(f) * 512 + lane * 8))

  // ---- QKV weight loads issued immediately (independent of everything)
  s16x8 bwq[3][4];
#pragma unroll
  for (int ii = 0; ii < 3; ++ii)
#pragma unroll
    for (int kt = 0; kt < 4; ++kt)
      bwq[ii][kt] = *WPK((w * 3 + ii) * 4 + kt);

  // ---- load x -> XF (fp32)
  {
#pragma unroll
    for (int i = t; i < 1024; i += 512) {
      const int row = i >> 5, c4i = i & 31;
      *(float4*)(XF + row * 132 + c4i * 4) =
          *(const float4*)(x + (size_t)n * (SEQL * DM) + i * 4);
    }
  }
  __syncthreads();

  // ---- LN1 -> AB
  ln_to_bf16(XF, AB, ln1_g, ln1_b, r16, cb8);
  __syncthreads();

  // ---- QKV GEMM: 24 N-tiles, 3 per wave (weights preloaded).
  {
    s16x8 a[2][4];
#pragma unroll
    for (int mt = 0; mt < 2; ++mt)
#pragma unroll
      for (int kt = 0; kt < 4; ++kt)
        a[mt][kt] = *(const s16x8*)(AB + (mt * 16 + c) * 136 + kt * 32 + q * 8);
#pragma unroll
    for (int ii = 0; ii < 3; ++ii) {
      const int n0 = (w * 3 + ii) * 16;
      f32x4 acc0 = {0.f, 0.f, 0.f, 0.f}, acc1 = {0.f, 0.f, 0.f, 0.f};
#pragma unroll
      for (int kt = 0; kt < 4; ++kt) {
        acc0 = MFMA16(a[0][kt], bwq[ii][kt], acc0);
        acc1 = MFMA16(a[1][kt], bwq[ii][kt], acc1);
      }
      const float bias = qkv_b[n0 + c];
      if (n0 < 128) {            // Q
#pragma unroll
        for (int i = 0; i < 4; ++i) {
          Qb[(q * 4 + i) * 136 + n0 + c] = f2bf(acc0[i] + bias);
          Qb[(16 + q * 4 + i) * 136 + n0 + c] = f2bf(acc1[i] + bias);
        }
      } else if (n0 < 256) {     // K
        const int cc = n0 - 128 + c;
#pragma unroll
        for (int i = 0; i < 4; ++i) {
          Kb[(q * 4 + i) * 136 + cc] = f2bf(acc0[i] + bias);
          Kb[(16 + q * 4 + i) * 136 + cc] = f2bf(acc1[i] + bias);
        }
      } else {                   // V -> Vt transposed
        const int d = n0 - 256 + c;
        s16x4 p0, p1;
#pragma unroll
        for (int i = 0; i < 4; ++i) { p0[i] = f2bf(acc0[i] + bias); p1[i] = f2bf(acc1[i] + bias); }
        *(s16x4*)(Vt + d * 40 + q * 4) = p0;
        *(s16x4*)(Vt + d * 40 + 16 + q * 4) = p1;
      }
    }
  }
  __syncthreads();

  // ---- scores S = Q K^T / sqrt(128). 4 tiles on waves 0-3.
  if (w < 4) {
    const int mt = w & 1, nt = w >> 1;
    s16x8 aq[4], bk[4];
#pragma unroll
    for (int kt = 0; kt < 4; ++kt) {
      aq[kt] = *(const s16x8*)(Qb + (mt * 16 + c) * 136 + kt * 32 + q * 8);
      bk[kt] = *(const s16x8*)(Kb + (nt * 16 + c) * 136 + kt * 32 + q * 8);
    }
    f32x4 acc = {0.f, 0.f, 0.f, 0.f};
#pragma unroll
    for (int kt = 0; kt < 4; ++kt) acc = MFMA16(aq[kt], bk[kt], acc);
#pragma unroll
    for (int i = 0; i < 4; ++i)
      Sf[(mt * 16 + q * 4 + i) * 36 + nt * 16 + c] = acc[i] * 0.08838834764831845f;
  }
  __syncthreads();

  // ---- softmax rows of Sf -> Pb (threads 0..255)
  if (t < 256) {
    const int r8 = t >> 3, c4 = (t & 7) * 4;
    float4 sv = *(const float4*)(Sf + r8 * 36 + c4);
    float mx = fmaxf(fmaxf(sv.x, sv.y), fmaxf(sv.z, sv.w));
    mx = fmaxf(mx, __shfl_xor(mx, 1));
    mx = fmaxf(mx, __shfl_xor(mx, 2));
    mx = fmaxf(mx, __shfl_xor(mx, 4));
    float e0 = expf(sv.x - mx), e1 = expf(sv.y - mx), e2 = expf(sv.z - mx), e3 = expf(sv.w - mx);
    float sum = e0 + e1 + e2 + e3;
    sum += __shfl_xor(sum, 1);
    sum += __shfl_xor(sum, 2);
    sum += __shfl_xor(sum, 4);
    const float inv = 1.f / sum;
    s16x4 pw; pw[0] = f2bf(e0 * inv); pw[1] = f2bf(e1 * inv); pw[2] = f2bf(e2 * inv); pw[3] = f2bf(e3 * inv);
    *(s16x4*)(Pb + r8 * 40 + c4) = pw;
  }
  __syncthreads();

  // ---- attn = P @ V (1 d-tile per wave) + early proj-weight loads
  s16x8 bwp[4];
  {
#pragma unroll
    for (int kt = 0; kt < 4; ++kt) bwp[kt] = *WPK(F_OUT + w * 4 + kt);
    s16x8 ap0 = *(const s16x8*)(Pb + c * 40 + q * 8);
    s16x8 ap1 = *(const s16x8*)(Pb + (16 + c) * 40 + q * 8);
    const int d0 = w * 16;
    s16x8 bv = *(const s16x8*)(Vt + (d0 + c) * 40 + q * 8);
    f32x4 acc0 = {0.f, 0.f, 0.f, 0.f}, acc1 = {0.f, 0.f, 0.f, 0.f};
    acc0 = MFMA16(ap0, bv, acc0);
    acc1 = MFMA16(ap1, bv, acc1);
#pragma unroll
    for (int i = 0; i < 4; ++i) {
      Qb[(q * 4 + i) * 136 + d0 + c] = f2bf(acc0[i]);
      Qb[(16 + q * 4 + i) * 136 + d0 + c] = f2bf(acc1[i]);
    }
  }
  __syncthreads();

  // ---- proj: XF += attn @ out_w^T + out_b (weights preloaded)
  {
    s16x8 aa[2][4];
#pragma unroll
    for (int mt = 0; mt < 2; ++mt)
#pragma unroll
      for (int kt = 0; kt < 4; ++kt)
        aa[mt][kt] = *(const s16x8*)(Qb + (mt * 16 + c) * 136 + kt * 32 + q * 8);
    const int n0 = w * 16;
    f32x4 acc0 = {0.f, 0.f, 0.f, 0.f}, acc1 = {0.f, 0.f, 0.f, 0.f};
#pragma unroll
    for (int kt = 0; kt < 4; ++kt) {
      acc0 = MFMA16(aa[0][kt], bwp[kt], acc0);
      acc1 = MFMA16(aa[1][kt], bwp[kt], acc1);
    }
    const float bias = out_b[n0 + c];
#pragma unroll
    for (int i = 0; i < 4; ++i) {
      XF[(q * 4 + i) * 132 + n0 + c] += acc0[i] + bias;
      XF[(16 + q * 4 + i) * 132 + n0 + c] += acc1[i] + bias;
    }
  }
  __syncthreads();

  // ---- LN2 -> AB
  ln_to_bf16(XF, AB, ln2_g, ln2_b, r16, cb8);
  __syncthreads();

  // ---- FFN: two 256-col chunks; all weight frags hoisted per chunk.
  {
    s16x8 af[2][4];
#pragma unroll
    for (int mt = 0; mt < 2; ++mt)
#pragma unroll
      for (int kt = 0; kt < 4; ++kt)
        af[mt][kt] = *(const s16x8*)(AB + (mt * 16 + c) * 136 + kt * 32 + q * 8);
    f32x4 facc0 = {0.f, 0.f, 0.f, 0.f}, facc1 = {0.f, 0.f, 0.f, 0.f};

    for (int ch = 0; ch < 2; ++ch) {
      s16x8 bw1[2][4], bw2[8];
#pragma unroll
      for (int ii = 0; ii < 2; ++ii)
#pragma unroll
        for (int kt = 0; kt < 4; ++kt)
          bw1[ii][kt] = *WPK(F_FF1 + (ch * 16 + w * 2 + ii) * 4 + kt);
#pragma unroll
      for (int kt = 0; kt < 8; ++kt)
        bw2[kt] = *WPK(F_FF2 + w * 16 + ch * 8 + kt);

#pragma unroll
      for (int ii = 0; ii < 2; ++ii) {
        const int ntl = w * 2 + ii;
        const int n0g = ch * 256 + ntl * 16;
        f32x4 acc0 = {0.f, 0.f, 0.f, 0.f}, acc1 = {0.f, 0.f, 0.f, 0.f};
#pragma unroll
        for (int kt = 0; kt < 4; ++kt) {
          acc0 = MFMA16(af[0][kt], bw1[ii][kt], acc0);
          acc1 = MFMA16(af[1][kt], bw1[ii][kt], acc1);
        }
        const float bias = ff1_b[n0g + c];
#pragma unroll
        for (int i = 0; i < 4; ++i) {
          Fb[(q * 4 + i) * 264 + ntl * 16 + c] = f2bf(gelu_exact(acc0[i] + bias));
          Fb[(16 + q * 4 + i) * 264 + ntl * 16 + c] = f2bf(gelu_exact(acc1[i] + bias));
        }
      }
      __syncthreads();
#pragma unroll
      for (int kt = 0; kt < 8; ++kt) {
        s16x8 a0 = *(const s16x8*)(Fb + c * 264 + kt * 32 + q * 8);
        s16x8 a1 = *(const s16x8*)(Fb + (16 + c) * 264 + kt * 32 + q * 8);
        facc0 = MFMA16(a0, bw2[kt], facc0);
        facc1 = MFMA16(a1, bw2[kt], facc1);
      }
      __syncthreads();
    }
    // epilogue fused with xt->bf16: AB = bf16(XF + facc + ff2_b)
    {
      const int n0 = w * 16;
      const float bias = ff2_b[n0 + c];
#pragma unroll
      for (int i = 0; i < 4; ++i) {
        const int r0 = q * 4 + i, r1 = 16 + q * 4 + i;
        AB[r0 * 136 + n0 + c] = f2bf(XF[r0 * 132 + n0 + c] + facc0[i] + bias);
        AB[r1 * 136 + n0 + c] = f2bf(XF[r1 * 132 + n0 + c] + facc1[i] + bias);
      }
    }
  }
  // early GAT weight loads (independent of the barrier below)
  s16x8 bwg[4];
#pragma unroll
  for (int kt = 0; kt < 4; ++kt) bwg[kt] = *WPK(F_GAT + w * 4 + kt);
  __syncthreads();

  // ---- GAT projection h = xt @ gat_w^T -> XF (fp32); h_out written coalesced below
  {
    s16x8 ag[2][4];
#pragma unroll
    for (int mt = 0; mt < 2; ++mt)
#pragma unroll
      for (int kt = 0; kt < 4; ++kt)
        ag[mt][kt] = *(const s16x8*)(AB + (mt * 16 + c) * 136 + kt * 32 + q * 8);
    const int n0 = w * 16;
    f32x4 acc0 = {0.f, 0.f, 0.f, 0.f}, acc1 = {0.f, 0.f, 0.f, 0.f};
#pragma unroll
    for (int kt = 0; kt < 4; ++kt) {
      acc0 = MFMA16(ag[0][kt], bwg[kt], acc0);
      acc1 = MFMA16(ag[1][kt], bwg[kt], acc1);
    }
#pragma unroll
    for (int i = 0; i < 4; ++i) {
      const int r0 = q * 4 + i, r1 = 16 + q * 4 + i;
      XF[r0 * 132 + n0 + c] = acc0[i];
      XF[r1 * 132 + n0 + c] = acc1[i];
    }
  }
  __syncthreads();

  // ---- h_out: coalesced bf16 write (full 128B lines), 16B per thread
  {
    const int row = t >> 4;
    const float* xr = XF + row * 132 + cb8;
    short o[8];
#pragma unroll
    for (int i = 0; i < 8; ++i) o[i] = f2bf(xr[i]);
    *(s16x8*)(h_out + ((size_t)n * SEQL + row) * DM + cb8) = *(s16x8*)o;
  }

  // ---- a_s / a_d
  if (t < 64) {
    const int row = t & 31;
    const float* vec = (t < 32) ? att_src : att_dst;
    const float* hr = XF + row * 132;
    float s = 0.f;
#pragma unroll
    for (int d = 0; d < DM; d += 4)
      s += hr[d] * vec[d] + hr[d + 1] * vec[d + 1] + hr[d + 2] * vec[d + 2] + hr[d + 3] * vec[d + 3];
    if (t < 32) as_out[n * SEQL + row] = s;
    else        ad_out[n * SEQL + row] = s;
  }
}

// fp32 -> bf16 tile-packed weight conversion: wpk[frag][lane][8].
__global__ void cvt_weights(const float* __restrict__ qkv_w, const float* __restrict__ out_w,
                            const float* __restrict__ ff1_w, const float* __restrict__ ff2_w,
                            const float* __restrict__ gat_w, short* __restrict__ wpk) {
  const int u = blockIdx.x * 256 + threadIdx.x;
  if (u >= NFRAG * 64) return;
  const int f = u >> 6, lane = u & 63;
  const int q = lane >> 4, c = lane & 15;
  const float* src; int row, kt, ld;
  if (f < F_OUT)       { src = qkv_w; ld = 128; int g = f;         row = (g >> 2) * 16 + c; kt = g & 3; }
  else if (f < F_FF1)  { src = out_w; ld = 128; int g = f - F_OUT; row = (g >> 2) * 16 + c; kt = g & 3; }
  else if (f < F_FF2)  { src = ff1_w; ld = 128; int g = f - F_FF1; row = (g >> 2) * 16 + c; kt = g & 3; }
  else if (f < F_GAT)  { src = ff2_w; ld = 512; int g = f - F_FF2; row = (g >> 4) * 16 + c; kt = g & 15; }
  else                 { src = gat_w; ld = 128; int g = f - F_GAT; row = (g >> 2) * 16 + c; kt = g & 3; }
  const float* p = src + row * ld + kt * 32 + q * 8;
  const float4 v0 = *(const float4*)p;
  const float4 v1 = *(const float4*)(p + 4);
  s16x8 o;
  o[0] = f2bf(v0.x); o[1] = f2bf(v0.y); o[2] = f2bf(v0.z); o[3] = f2bf(v0.w);
  o[4] = f2bf(v1.x); o[5] = f2bf(v1.y); o[6] = f2bf(v1.z); o[7] = f2bf(v1.w);
  *(s16x8*)(wpk + (size_t)f * 512 + lane * 8) = o;
}

__global__ void zero_counts(int* counts) {
  int i = blockIdx.x * 256 + threadIdx.x;
  if (i < KNODES) counts[i] = 0;
}

__global__ void hist_kernel(const int* __restrict__ ei, int* counts) {
  int i = blockIdx.x * 256 + threadIdx.x;
  if (i < NETOT) {
    int dst = (i < NEDGE) ? ei[NEDGE + i] : (i - NEDGE);
    atomicAdd(&counts[dst], 1);
  }
}

__global__ void scan_kernel(const int* __restrict__ counts, int* offs, int* cursor) {
  __shared__ int tmp[1024];
  const int t = threadIdx.x;
  const int base = t * 4;
  int c0 = counts[base], c1 = counts[base + 1], c2 = counts[base + 2], c3 = counts[base + 3];
  const int s = c0 + c1 + c2 + c3;
  tmp[t] = s;
  __syncthreads();
  for (int off = 1; off < 1024; off <<= 1) {
    int v = (t >= off) ? tmp[t - off] : 0;
    __syncthreads();
    tmp[t] += v;
    __syncthreads();
  }
  int o = tmp[t] - s;
  offs[base] = o; cursor[base] = o; o += c0;
  offs[base + 1] = o; cursor[base + 1] = o; o += c1;
  offs[base + 2] = o; cursor[base + 2] = o; o += c2;
  offs[base + 3] = o; cursor[base + 3] = o; o += c3;
  if (t == 1023) offs[KNODES] = o;
}

__global__ void scatter_kernel(const int* __restrict__ ei, int* cursor, int* __restrict__ csr) {
  int i = blockIdx.x * 256 + threadIdx.x;
  if (i < NETOT) {
    int src, dst;
    if (i < NEDGE) { src = ei[i]; dst = ei[NEDGE + i]; }
    else           { src = dst = i - NEDGE; }
    int pos = atomicAdd(&cursor[dst], 1);
    csr[pos] = src;
  }
}

// GAT aggregation: grid (KNODES, 2); single pass, deferred norm.
// Thread map: r = t>>4 (16 L-rows), cl = (t&15)*8 (col block of 8 bf16).
// One dwordx4 load per edge per thread; 4-edge-deep software pipeline.
#define ECH 32
__global__ __launch_bounds__(256) void gat_aggregate(
    const short* __restrict__ h, const float* __restrict__ as_g, const float* __restrict__ ad_g,
    const int* __restrict__ offs, const int* __restrict__ csr,
    const float* __restrict__ gat_b, float* __restrict__ out) {
  __shared__ float ad_s[16];
  __shared__ float ew[ECH * 17];
  __shared__ int   srcs[ECH];
  __shared__ float dred[16 * 33];
  __shared__ float invd[16];

  const int t = threadIdx.x;
  const int n = blockIdx.x;
  const int l0 = blockIdx.y * 16;
  if (t < 16) ad_s[t] = ad_g[n * SEQL + l0 + t];
  __syncthreads();
  const int beg = offs[n], end = offs[n + 1];

  const int s = t >> 3, lq = t & 7;
  float dpart0 = 0.f, dpart1 = 0.f;

  const int r = t >> 4;             // 0..15: which L-row in this half
  const int cl = (t & 15) * 8;      // col block (8 bf16 = 16B)
  const size_t roff = (size_t)(l0 + r) * DM + cl;
  float acc[8];
#pragma unroll
  for (int j = 0; j < 8; ++j) acc[j] = 0.f;

  for (int cb = beg; cb < end; cb += ECH) {
    const int cnt = min(ECH, end - cb);
    if (s < cnt) {
      const int src = csr[cb + s];
      if (lq == 0) srcs[s] = src;
      const float2 av = *(const float2*)(as_g + src * SEQL + l0 + lq * 2);
      float v0 = av.x + ad_s[lq * 2];
      v0 = v0 > 0.f ? v0 : 0.2f * v0;
      const float e0 = __expf(v0);
      float v1 = av.y + ad_s[lq * 2 + 1];
      v1 = v1 > 0.f ? v1 : 0.2f * v1;
      const float e1 = __expf(v1);
      ew[s * 17 + lq * 2] = e0;
      ew[s * 17 + lq * 2 + 1] = e1;
      dpart0 += e0; dpart1 += e1;
    }
    __syncthreads();

    // 4-deep software pipeline; consumption strictly ss-ascending (FP order
    // identical to the sequential version).
    s16x8 p0, p1, p2, p3;
#define GLOAD(dst, idx)                                                        \
    if ((idx) < cnt)                                                           \
      dst = *(const s16x8*)(h + (size_t)srcs[idx] * (SEQL * DM) + roff)
    GLOAD(p0, 0); GLOAD(p1, 1); GLOAD(p2, 2); GLOAD(p3, 3);

#define CONSUME(p, idx)                                                        \
    if ((idx) < cnt) {                                                         \
      const float wgt = ew[(idx) * 17 + r];                                    \
      const unsigned* pu = (const unsigned*)&(p);                              \
      _Pragma("unroll")                                                        \
      for (int j = 0; j < 4; ++j) {                                           \
        acc[2 * j]     += wgt * __uint_as_float(pu[j] << 16);                  \
        acc[2 * j + 1] += wgt * __uint_as_float(pu[j] & 0xFFFF0000u);          \
      }                                                                        \
    }

    for (int ss = 0; ss < cnt; ss += 4) {
      s16x8 n0, n1, n2, n3;
      GLOAD(n0, ss + 4); GLOAD(n1, ss + 5); GLOAD(n2, ss + 6); GLOAD(n3, ss + 7);
      CONSUME(p0, ss);
      CONSUME(p1, ss + 1);
      CONSUME(p2, ss + 2);
      CONSUME(p3, ss + 3);
      p0 = n0; p1 = n1; p2 = n2; p3 = n3;
    }
#undef GLOAD
#undef CONSUME
    __syncthreads();
  }

  dred[(lq * 2) * 33 + s] = dpart0;
  dred[(lq * 2 + 1) * 33 + s] = dpart1;
  __syncthreads();
  if (t < 16) {
    float sum = 0.f;
#pragma unroll
    for (int s2 = 0; s2 < 32; ++s2) sum += dred[t * 33 + s2];
    invd[t] = 1.f / (sum + 1e-16f);
  }
  __syncthreads();

  const float iv = invd[r];
  float4 b0 = *(const float4*)(gat_b + cl);
  float4 b1 = *(const float4*)(gat_b + cl + 4);
  float4 o0, o1;
  o0.x = acc[0] * iv + b0.x; o0.y = acc[1] * iv + b0.y;
  o0.z = acc[2] * iv + b0.z; o0.w = acc[3] * iv + b0.w;
  o1.x = acc[4] * iv + b1.x; o1.y = acc[5] * iv + b1.y;
  o1.z = acc[6] * iv + b1.z; o1.w = acc[7] * iv + b1.w;
  float* op = out + (size_t)n * (SEQL * DM) + (l0 + r) * DM + cl;
  *(float4*)op = o0;
  *(float4*)(op + 4) = o1;
}

extern "C" void kernel_launch(void* const* d_in, const int* in_sizes, int n_in,
                              void* d_out, int out_size, void* d_ws, size_t ws_size,
                              hipStream_t stream) {
  const float* x       = (const float*)d_in[0];
  const int* ei        = (const int*)d_in[1];
  const float* ln1_g   = (const float*)d_in[2];
  const float* ln1_b   = (const float*)d_in[3];
  const float* qkv_w   = (const float*)d_in[4];
  const float* qkv_b   = (const float*)d_in[5];
  const float* out_w   = (const float*)d_in[6];
  const float* out_b   = (const float*)d_in[7];
  const float* ln2_g   = (const float*)d_in[8];
  const float* ln2_b   = (const float*)d_in[9];
  const float* ff1_w   = (const float*)d_in[10];
  const float* ff1_b   = (const float*)d_in[11];
  const float* ff2_w   = (const float*)d_in[12];
  const float* ff2_b   = (const float*)d_in[13];
  const float* gat_w   = (const float*)d_in[14];
  const float* att_src = (const float*)d_in[15];
  const float* att_dst = (const float*)d_in[16];
  const float* gat_b   = (const float*)d_in[17];
  float* out = (float*)d_out;

  short* h    = (short*)d_ws;                             // 16777216 shorts (bf16)
  float* as_g = (float*)(h + (size_t)KNODES * SEQL * DM); // 131072 floats
  float* ad_g = as_g + KNODES * SEQL;                     // 131072
  int* counts = (int*)(ad_g + KNODES * SEQL);             // 4096
  int* offs   = counts + KNODES;                          // 4097
  int* cursor = offs + KNODES + 1;                        // 4096
  int* csr    = cursor + KNODES;                          // 69632
  size_t wofs = (size_t)((char*)(csr + NETOT) - (char*)d_ws);
  wofs = (wofs + 1023) & ~(size_t)1023;
  short* wpk = (short*)((char*)d_ws + wofs);              // 416*512 shorts

  cvt_weights<<<(NFRAG * 64 + 255) / 256, 256, 0, stream>>>(qkv_w, out_w, ff1_w, ff2_w, gat_w, wpk);
  zero_counts<<<(KNODES + 255) / 256, 256, 0, stream>>>(counts);
  hist_kernel<<<(NETOT + 255) / 256, 256, 0, stream>>>(ei, counts);
  scan_kernel<<<1, 1024, 0, stream>>>(counts, offs, cursor);
  scatter_kernel<<<(NETOT + 255) / 256, 256, 0, stream>>>(ei, cursor, csr);
  temporal_kernel<<<KNODES, 512, 0, stream>>>(
      x, ln1_g, ln1_b, wpk, qkv_b, out_b, ln2_g, ln2_b,
      ff1_b, ff2_b, att_src, att_dst, h, as_g, ad_g);
  gat_aggregate<<<dim3(KNODES, 2), 256, 0, stream>>>(h, as_g, ad_g, offs, csr, gat_b, out);
}

// Round 3
// 326.157 us; speedup vs baseline: 1.1983x; 1.0960x over previous
//
#include <hip/hip_runtime.h>

#define KNODES 4096
#define SEQL 32
#define DM 128
#define DFF 512
#define NEDGE 65536
#define NETOT (NEDGE + KNODES)

typedef float f32x4 __attribute__((ext_vector_type(4)));
typedef short s16x8 __attribute__((ext_vector_type(8)));
typedef short s16x4 __attribute__((ext_vector_type(4)));

#define MFMA16(a, b, c) __builtin_amdgcn_mfma_f32_16x16x32_bf16(a, b, c, 0, 0, 0)

// packed-weight fragment table (frag = 512 shorts = 64 lanes x 16B):
//  qkv: f = tile*4+kt            tiles 0..23   (rows n0=tile*16 of qkv_w[384][128])
//  out: f = 96 + tile*4+kt       tiles 0..7
//  ff1: f = 128 + tile*4+kt      tiles 0..31
//  ff2: f = 256 + ntile*16+kt    ntiles 0..7, kt 0..15 (K=512)
//  gat: f = 384 + tile*4+kt      tiles 0..7
#define F_OUT 96
#define F_FF1 128
#define F_FF2 256
#define F_GAT 384
#define NFRAG 416

__device__ __forceinline__ short f2bf(float f) {
  union { float f; unsigned u; } v; v.f = f;
  unsigned r = (v.u + 0x7FFFu + ((v.u >> 16) & 1u)) >> 16;
  return (short)r;
}

__device__ __forceinline__ float gelu_exact(float v) {
  return 0.5f * v * (1.f + erff(v * 0.70710678118654752440f));
}

// LayerNorm one row-slice: 16 lanes per row, 8 elems per lane.
__device__ __forceinline__ void ln_to_bf16(const float* XF, short* AB,
                                           const float* __restrict__ g,
                                           const float* __restrict__ b,
                                           int r, int cb) {
  const float* xr = XF + r * 132 + cb;
  float v[8]; float s = 0.f, ss = 0.f;
#pragma unroll
  for (int i = 0; i < 8; ++i) { v[i] = xr[i]; s += v[i]; ss += v[i] * v[i]; }
  s += __shfl_xor(s, 1); ss += __shfl_xor(ss, 1);
  s += __shfl_xor(s, 2); ss += __shfl_xor(ss, 2);
  s += __shfl_xor(s, 4); ss += __shfl_xor(ss, 4);
  s += __shfl_xor(s, 8); ss += __shfl_xor(ss, 8);
  const float mean = s * (1.f / 128.f);
  const float var = ss * (1.f / 128.f) - mean * mean;
  const float rs = rsqrtf(var + 1e-5f);
  const float* gp = g + cb; const float* bp = b + cb;
  short o[8];
#pragma unroll
  for (int i = 0; i < 8; ++i) o[i] = f2bf((v[i] - mean) * rs * gp[i] + bp[i]);
  *(s16x8*)(AB + r * 136 + cb) = *(s16x8*)o;
}

// LDS map (bytes), total 53248:
//  XF @0 fp32[32][132]; AB/Sf/Pb @16896; Qb @25600; Kb @34304 (Fb aliases Qb+Kb);
//  Vt @43008 bf16[128][40].
__global__ __launch_bounds__(512, 4) void temporal_kernel(
    const float* __restrict__ x,
    const float* __restrict__ ln1_g, const float* __restrict__ ln1_b,
    const short* __restrict__ wpk, const float* __restrict__ qkv_b,
    const float* __restrict__ out_b,
    const float* __restrict__ ln2_g, const float* __restrict__ ln2_b,
    const float* __restrict__ ff1_b, const float* __restrict__ ff2_b,
    const float* __restrict__ att_src, const float* __restrict__ att_dst,
    short* __restrict__ h_out, float* __restrict__ as_out, float* __restrict__ ad_out) {
  __shared__ __align__(16) char smem[53248];
  float* XF = (float*)smem;
  short* AB = (short*)(smem + 16896);
  float* Sf = (float*)(smem + 16896);
  short* Pb = (short*)(smem + 21504);
  short* Qb = (short*)(smem + 25600);
  short* Kb = (short*)(smem + 34304);
  short* Fb = (short*)(smem + 25600);
  short* Vt = (short*)(smem + 43008);

  const int t = threadIdx.x;
  const int w = t >> 6;                 // 8 waves
  const int lane = t & 63;
  const int q = lane >> 4, c = lane & 15;
  const int n = blockIdx.x;
  const int r16 = t >> 4, cb8 = (t & 15) * 8;

#define WPK(f) ((const s16x8*)(wpk + (size_t)(f) * 512 + lane * 8))

  // ---- QKV weight loads issued immediately (independent of everything)
  s16x8 bwq[3][4];
#pragma unroll
  for (int ii = 0; ii < 3; ++ii)
#pragma unroll
    for (int kt = 0; kt < 4; ++kt)
      bwq[ii][kt] = *WPK((w * 3 + ii) * 4 + kt);

  // ---- load x -> XF (fp32)
  {
#pragma unroll
    for (int i = t; i < 1024; i += 512) {
      const int row = i >> 5, c4i = i & 31;
      *(float4*)(XF + row * 132 + c4i * 4) =
          *(const float4*)(x + (size_t)n * (SEQL * DM) + i * 4);
    }
  }
  __syncthreads();

  // ---- LN1 -> AB
  ln_to_bf16(XF, AB, ln1_g, ln1_b, r16, cb8);
  __syncthreads();

  // ---- QKV GEMM: 24 N-tiles, 3 per wave (weights preloaded).
  {
    s16x8 a[2][4];
#pragma unroll
    for (int mt = 0; mt < 2; ++mt)
#pragma unroll
      for (int kt = 0; kt < 4; ++kt)
        a[mt][kt] = *(const s16x8*)(AB + (mt * 16 + c) * 136 + kt * 32 + q * 8);
#pragma unroll
    for (int ii = 0; ii < 3; ++ii) {
      const int n0 = (w * 3 + ii) * 16;
      f32x4 acc0 = {0.f, 0.f, 0.f, 0.f}, acc1 = {0.f, 0.f, 0.f, 0.f};
#pragma unroll
      for (int kt = 0; kt < 4; ++kt) {
        acc0 = MFMA16(a[0][kt], bwq[ii][kt], acc0);
        acc1 = MFMA16(a[1][kt], bwq[ii][kt], acc1);
      }
      const float bias = qkv_b[n0 + c];
      if (n0 < 128) {            // Q
#pragma unroll
        for (int i = 0; i < 4; ++i) {
          Qb[(q * 4 + i) * 136 + n0 + c] = f2bf(acc0[i] + bias);
          Qb[(16 + q * 4 + i) * 136 + n0 + c] = f2bf(acc1[i] + bias);
        }
      } else if (n0 < 256) {     // K
        const int cc = n0 - 128 + c;
#pragma unroll
        for (int i = 0; i < 4; ++i) {
          Kb[(q * 4 + i) * 136 + cc] = f2bf(acc0[i] + bias);
          Kb[(16 + q * 4 + i) * 136 + cc] = f2bf(acc1[i] + bias);
        }
      } else {                   // V -> Vt transposed
        const int d = n0 - 256 + c;
        s16x4 p0, p1;
#pragma unroll
        for (int i = 0; i < 4; ++i) { p0[i] = f2bf(acc0[i] + bias); p1[i] = f2bf(acc1[i] + bias); }
        *(s16x4*)(Vt + d * 40 + q * 4) = p0;
        *(s16x4*)(Vt + d * 40 + 16 + q * 4) = p1;
      }
    }
  }
  __syncthreads();

  // ---- scores S = Q K^T / sqrt(128). 4 tiles on waves 0-3.
  if (w < 4) {
    const int mt = w & 1, nt = w >> 1;
    s16x8 aq[4], bk[4];
#pragma unroll
    for (int kt = 0; kt < 4; ++kt) {
      aq[kt] = *(const s16x8*)(Qb + (mt * 16 + c) * 136 + kt * 32 + q * 8);
      bk[kt] = *(const s16x8*)(Kb + (nt * 16 + c) * 136 + kt * 32 + q * 8);
    }
    f32x4 acc = {0.f, 0.f, 0.f, 0.f};
#pragma unroll
    for (int kt = 0; kt < 4; ++kt) acc = MFMA16(aq[kt], bk[kt], acc);
#pragma unroll
    for (int i = 0; i < 4; ++i)
      Sf[(mt * 16 + q * 4 + i) * 36 + nt * 16 + c] = acc[i] * 0.08838834764831845f;
  }
  __syncthreads();

  // ---- softmax rows of Sf -> Pb (threads 0..255)
  if (t < 256) {
    const int r8 = t >> 3, c4 = (t & 7) * 4;
    float4 sv = *(const float4*)(Sf + r8 * 36 + c4);
    float mx = fmaxf(fmaxf(sv.x, sv.y), fmaxf(sv.z, sv.w));
    mx = fmaxf(mx, __shfl_xor(mx, 1));
    mx = fmaxf(mx, __shfl_xor(mx, 2));
    mx = fmaxf(mx, __shfl_xor(mx, 4));
    float e0 = expf(sv.x - mx), e1 = expf(sv.y - mx), e2 = expf(sv.z - mx), e3 = expf(sv.w - mx);
    float sum = e0 + e1 + e2 + e3;
    sum += __shfl_xor(sum, 1);
    sum += __shfl_xor(sum, 2);
    sum += __shfl_xor(sum, 4);
    const float inv = 1.f / sum;
    s16x4 pw; pw[0] = f2bf(e0 * inv); pw[1] = f2bf(e1 * inv); pw[2] = f2bf(e2 * inv); pw[3] = f2bf(e3 * inv);
    *(s16x4*)(Pb + r8 * 40 + c4) = pw;
  }
  __syncthreads();

  // ---- attn = P @ V (1 d-tile per wave) + early proj-weight loads
  s16x8 bwp[4];
  {
#pragma unroll
    for (int kt = 0; kt < 4; ++kt) bwp[kt] = *WPK(F_OUT + w * 4 + kt);
    s16x8 ap0 = *(const s16x8*)(Pb + c * 40 + q * 8);
    s16x8 ap1 = *(const s16x8*)(Pb + (16 + c) * 40 + q * 8);
    const int d0 = w * 16;
    s16x8 bv = *(const s16x8*)(Vt + (d0 + c) * 40 + q * 8);
    f32x4 acc0 = {0.f, 0.f, 0.f, 0.f}, acc1 = {0.f, 0.f, 0.f, 0.f};
    acc0 = MFMA16(ap0, bv, acc0);
    acc1 = MFMA16(ap1, bv, acc1);
#pragma unroll
    for (int i = 0; i < 4; ++i) {
      Qb[(q * 4 + i) * 136 + d0 + c] = f2bf(acc0[i]);
      Qb[(16 + q * 4 + i) * 136 + d0 + c] = f2bf(acc1[i]);
    }
  }
  __syncthreads();

  // ---- proj: XF += attn @ out_w^T + out_b (weights preloaded)
  {
    s16x8 aa[2][4];
#pragma unroll
    for (int mt = 0; mt < 2; ++mt)
#pragma unroll
      for (int kt = 0; kt < 4; ++kt)
        aa[mt][kt] = *(const s16x8*)(Qb + (mt * 16 + c) * 136 + kt * 32 + q * 8);
    const int n0 = w * 16;
    f32x4 acc0 = {0.f, 0.f, 0.f, 0.f}, acc1 = {0.f, 0.f, 0.f, 0.f};
#pragma unroll
    for (int kt = 0; kt < 4; ++kt) {
      acc0 = MFMA16(aa[0][kt], bwp[kt], acc0);
      acc1 = MFMA16(aa[1][kt], bwp[kt], acc1);
    }
    const float bias = out_b[n0 + c];
#pragma unroll
    for (int i = 0; i < 4; ++i) {
      XF[(q * 4 + i) * 132 + n0 + c] += acc0[i] + bias;
      XF[(16 + q * 4 + i) * 132 + n0 + c] += acc1[i] + bias;
    }
  }
  __syncthreads();

  // ---- LN2 -> AB
  ln_to_bf16(XF, AB, ln2_g, ln2_b, r16, cb8);
  __syncthreads();

  // ---- FFN: two 256-col chunks; all weight frags hoisted per chunk.
  {
    s16x8 af[2][4];
#pragma unroll
    for (int mt = 0; mt < 2; ++mt)
#pragma unroll
      for (int kt = 0; kt < 4; ++kt)
        af[mt][kt] = *(const s16x8*)(AB + (mt * 16 + c) * 136 + kt * 32 + q * 8);
    f32x4 facc0 = {0.f, 0.f, 0.f, 0.f}, facc1 = {0.f, 0.f, 0.f, 0.f};

    for (int ch = 0; ch < 2; ++ch) {
      s16x8 bw1[2][4], bw2[8];
#pragma unroll
      for (int ii = 0; ii < 2; ++ii)
#pragma unroll
        for (int kt = 0; kt < 4; ++kt)
          bw1[ii][kt] = *WPK(F_FF1 + (ch * 16 + w * 2 + ii) * 4 + kt);
#pragma unroll
      for (int kt = 0; kt < 8; ++kt)
        bw2[kt] = *WPK(F_FF2 + w * 16 + ch * 8 + kt);

#pragma unroll
      for (int ii = 0; ii < 2; ++ii) {
        const int ntl = w * 2 + ii;
        const int n0g = ch * 256 + ntl * 16;
        f32x4 acc0 = {0.f, 0.f, 0.f, 0.f}, acc1 = {0.f, 0.f, 0.f, 0.f};
#pragma unroll
        for (int kt = 0; kt < 4; ++kt) {
          acc0 = MFMA16(af[0][kt], bw1[ii][kt], acc0);
          acc1 = MFMA16(af[1][kt], bw1[ii][kt], acc1);
        }
        const float bias = ff1_b[n0g + c];
#pragma unroll
        for (int i = 0; i < 4; ++i) {
          Fb[(q * 4 + i) * 264 + ntl * 16 + c] = f2bf(gelu_exact(acc0[i] + bias));
          Fb[(16 + q * 4 + i) * 264 + ntl * 16 + c] = f2bf(gelu_exact(acc1[i] + bias));
        }
      }
      __syncthreads();
#pragma unroll
      for (int kt = 0; kt < 8; ++kt) {
        s16x8 a0 = *(const s16x8*)(Fb + c * 264 + kt * 32 + q * 8);
        s16x8 a1 = *(const s16x8*)(Fb + (16 + c) * 264 + kt * 32 + q * 8);
        facc0 = MFMA16(a0, bw2[kt], facc0);
        facc1 = MFMA16(a1, bw2[kt], facc1);
      }
      __syncthreads();
    }
    // epilogue fused with xt->bf16: AB = bf16(XF + facc + ff2_b)
    {
      const int n0 = w * 16;
      const float bias = ff2_b[n0 + c];
#pragma unroll
      for (int i = 0; i < 4; ++i) {
        const int r0 = q * 4 + i, r1 = 16 + q * 4 + i;
        AB[r0 * 136 + n0 + c] = f2bf(XF[r0 * 132 + n0 + c] + facc0[i] + bias);
        AB[r1 * 136 + n0 + c] = f2bf(XF[r1 * 132 + n0 + c] + facc1[i] + bias);
      }
    }
  }
  // early GAT weight loads (independent of the barrier below)
  s16x8 bwg[4];
#pragma unroll
  for (int kt = 0; kt < 4; ++kt) bwg[kt] = *WPK(F_GAT + w * 4 + kt);
  __syncthreads();

  // ---- GAT projection h = xt @ gat_w^T -> XF (fp32); h_out written coalesced below
  {
    s16x8 ag[2][4];
#pragma unroll
    for (int mt = 0; mt < 2; ++mt)
#pragma unroll
      for (int kt = 0; kt < 4; ++kt)
        ag[mt][kt] = *(const s16x8*)(AB + (mt * 16 + c) * 136 + kt * 32 + q * 8);
    const int n0 = w * 16;
    f32x4 acc0 = {0.f, 0.f, 0.f, 0.f}, acc1 = {0.f, 0.f, 0.f, 0.f};
#pragma unroll
    for (int kt = 0; kt < 4; ++kt) {
      acc0 = MFMA16(ag[0][kt], bwg[kt], acc0);
      acc1 = MFMA16(ag[1][kt], bwg[kt], acc1);
    }
#pragma unroll
    for (int i = 0; i < 4; ++i) {
      const int r0 = q * 4 + i, r1 = 16 + q * 4 + i;
      XF[r0 * 132 + n0 + c] = acc0[i];
      XF[r1 * 132 + n0 + c] = acc1[i];
    }
  }
  __syncthreads();

  // ---- h_out: coalesced bf16 write (full 128B lines), 16B per thread
  {
    const int row = t >> 4;
    const float* xr = XF + row * 132 + cb8;
    short o[8];
#pragma unroll
    for (int i = 0; i < 8; ++i) o[i] = f2bf(xr[i]);
    *(s16x8*)(h_out + ((size_t)n * SEQL + row) * DM + cb8) = *(s16x8*)o;
  }

  // ---- a_s / a_d
  if (t < 64) {
    const int row = t & 31;
    const float* vec = (t < 32) ? att_src : att_dst;
    const float* hr = XF + row * 132;
    float s = 0.f;
#pragma unroll
    for (int d = 0; d < DM; d += 4)
      s += hr[d] * vec[d] + hr[d + 1] * vec[d + 1] + hr[d + 2] * vec[d + 2] + hr[d + 3] * vec[d + 3];
    if (t < 32) as_out[n * SEQL + row] = s;
    else        ad_out[n * SEQL + row] = s;
  }
}

// fp32 -> bf16 tile-packed weight conversion: wpk[frag][lane][8].
__global__ void cvt_weights(const float* __restrict__ qkv_w, const float* __restrict__ out_w,
                            const float* __restrict__ ff1_w, const float* __restrict__ ff2_w,
                            const float* __restrict__ gat_w, short* __restrict__ wpk) {
  const int u = blockIdx.x * 256 + threadIdx.x;
  if (u >= NFRAG * 64) return;
  const int f = u >> 6, lane = u & 63;
  const int q = lane >> 4, c = lane & 15;
  const float* src; int row, kt, ld;
  if (f < F_OUT)       { src = qkv_w; ld = 128; int g = f;         row = (g >> 2) * 16 + c; kt = g & 3; }
  else if (f < F_FF1)  { src = out_w; ld = 128; int g = f - F_OUT; row = (g >> 2) * 16 + c; kt = g & 3; }
  else if (f < F_FF2)  { src = ff1_w; ld = 128; int g = f - F_FF1; row = (g >> 2) * 16 + c; kt = g & 3; }
  else if (f < F_GAT)  { src = ff2_w; ld = 512; int g = f - F_FF2; row = (g >> 4) * 16 + c; kt = g & 15; }
  else                 { src = gat_w; ld = 128; int g = f - F_GAT; row = (g >> 2) * 16 + c; kt = g & 3; }
  const float* p = src + row * ld + kt * 32 + q * 8;
  const float4 v0 = *(const float4*)p;
  const float4 v1 = *(const float4*)(p + 4);
  s16x8 o;
  o[0] = f2bf(v0.x); o[1] = f2bf(v0.y); o[2] = f2bf(v0.z); o[3] = f2bf(v0.w);
  o[4] = f2bf(v1.x); o[5] = f2bf(v1.y); o[6] = f2bf(v1.z); o[7] = f2bf(v1.w);
  *(s16x8*)(wpk + (size_t)f * 512 + lane * 8) = o;
}

__global__ void zero_counts(int* counts) {
  int i = blockIdx.x * 256 + threadIdx.x;
  if (i < KNODES) counts[i] = 0;
}

__global__ void hist_kernel(const int* __restrict__ ei, int* counts) {
  int i = blockIdx.x * 256 + threadIdx.x;
  if (i < NETOT) {
    int dst = (i < NEDGE) ? ei[NEDGE + i] : (i - NEDGE);
    atomicAdd(&counts[dst], 1);
  }
}

__global__ void scan_kernel(const int* __restrict__ counts, int* offs, int* cursor) {
  __shared__ int tmp[1024];
  const int t = threadIdx.x;
  const int base = t * 4;
  int c0 = counts[base], c1 = counts[base + 1], c2 = counts[base + 2], c3 = counts[base + 3];
  const int s = c0 + c1 + c2 + c3;
  tmp[t] = s;
  __syncthreads();
  for (int off = 1; off < 1024; off <<= 1) {
    int v = (t >= off) ? tmp[t - off] : 0;
    __syncthreads();
    tmp[t] += v;
    __syncthreads();
  }
  int o = tmp[t] - s;
  offs[base] = o; cursor[base] = o; o += c0;
  offs[base + 1] = o; cursor[base + 1] = o; o += c1;
  offs[base + 2] = o; cursor[base + 2] = o; o += c2;
  offs[base + 3] = o; cursor[base + 3] = o; o += c3;
  if (t == 1023) offs[KNODES] = o;
}

__global__ void scatter_kernel(const int* __restrict__ ei, int* cursor, int* __restrict__ csr) {
  int i = blockIdx.x * 256 + threadIdx.x;
  if (i < NETOT) {
    int src, dst;
    if (i < NEDGE) { src = ei[i]; dst = ei[NEDGE + i]; }
    else           { src = dst = i - NEDGE; }
    int pos = atomicAdd(&cursor[dst], 1);
    csr[pos] = src;
  }
}

// GAT aggregation, XCD-pinned L-slicing:
// grid (8, KNODES), 64 threads. Block (lg, n) handles rows l = 4*lg .. 4*lg+3.
// Flat wg id = lg + 8*n -> default round-robin puts lg==k on XCD k, so each
// XCD's gather working set is 4 L-slices of h = 4 MB == its private L2.
// Per edge: 64 threads read 1 KB contiguous (4 rows x 256B); ss-ascending order.
#define ECH 16
__global__ __launch_bounds__(64) void gat_aggregate(
    const short* __restrict__ h, const float* __restrict__ as_g, const float* __restrict__ ad_g,
    const int* __restrict__ offs, const int* __restrict__ csr,
    const float* __restrict__ gat_b, float* __restrict__ out) {
  __shared__ float ew[ECH * 5];
  __shared__ int   srcs[ECH];

  const int t = threadIdx.x;            // 0..63
  const int lg = blockIdx.x;            // 0..7: l-group (XCD-pinned)
  const int n = blockIdx.y;
  const int l0 = lg * 4;

  const int s = t >> 2, lr = t & 3;     // ew-phase: edge slot, row
  const int r = t >> 4, cl = (t & 15) * 8;  // gather: row, col block (8 bf16)

  const float adv = ad_g[n * SEQL + l0 + lr];
  const int beg = offs[n], end = offs[n + 1];
  const size_t roff = (size_t)(l0 + r) * DM + cl;

  float dpart = 0.f;
  float acc[8];
#pragma unroll
  for (int j = 0; j < 8; ++j) acc[j] = 0.f;

  for (int cb = beg; cb < end; cb += ECH) {
    const int cnt = min(ECH, end - cb);
    if (s < cnt) {
      const int src = csr[cb + s];
      if (lr == 0) srcs[s] = src;
      float v = as_g[src * SEQL + l0 + lr] + adv;
      v = v > 0.f ? v : 0.2f * v;
      const float e = __expf(v);
      ew[s * 5 + lr] = e;
      dpart += e;
    }
    __syncthreads();

    // depth-4 software pipeline; consumption strictly ss-ascending.
    s16x8 p0, p1, p2, p3;
#define GLOAD(dst, idx)                                                        \
    if ((idx) < cnt)                                                           \
      dst = *(const s16x8*)(h + (size_t)srcs[idx] * (SEQL * DM) + roff)
    GLOAD(p0, 0); GLOAD(p1, 1); GLOAD(p2, 2); GLOAD(p3, 3);

#define CONSUME(p, idx)                                                        \
    if ((idx) < cnt) {                                                         \
      const float wgt = ew[(idx) * 5 + r];                                     \
      const unsigned* pu = (const unsigned*)&(p);                              \
      _Pragma("unroll")                                                        \
      for (int j = 0; j < 4; ++j) {                                           \
        acc[2 * j]     += wgt * __uint_as_float(pu[j] << 16);                  \
        acc[2 * j + 1] += wgt * __uint_as_float(pu[j] & 0xFFFF0000u);          \
      }                                                                        \
    }

    for (int ss = 0; ss < cnt; ss += 4) {
      s16x8 n0, n1, n2, n3;
      GLOAD(n0, ss + 4); GLOAD(n1, ss + 5); GLOAD(n2, ss + 6); GLOAD(n3, ss + 7);
      CONSUME(p0, ss);
      CONSUME(p1, ss + 1);
      CONSUME(p2, ss + 2);
      CONSUME(p3, ss + 3);
      p0 = n0; p1 = n1; p2 = n2; p3 = n3;
    }
#undef GLOAD
#undef CONSUME
    __syncthreads();
  }

  // denominator: sum over edge slots (lanes with same lr), then pick row r.
  dpart += __shfl_xor(dpart, 4);
  dpart += __shfl_xor(dpart, 8);
  dpart += __shfl_xor(dpart, 16);
  dpart += __shfl_xor(dpart, 32);
  const float iv = 1.f / (__shfl(dpart, r) + 1e-16f);

  const float4 b0 = *(const float4*)(gat_b + cl);
  const float4 b1 = *(const float4*)(gat_b + cl + 4);
  f32x4 o0, o1;
  o0[0] = acc[0] * iv + b0.x; o0[1] = acc[1] * iv + b0.y;
  o0[2] = acc[2] * iv + b0.z; o0[3] = acc[3] * iv + b0.w;
  o1[0] = acc[4] * iv + b1.x; o1[1] = acc[5] * iv + b1.y;
  o1[2] = acc[6] * iv + b1.z; o1[3] = acc[7] * iv + b1.w;
  float* op = out + (size_t)n * (SEQL * DM) + (l0 + r) * DM + cl;
  // non-temporal: keep the streamed 64 MB of out from evicting the h slice in L2
  __builtin_nontemporal_store(o0, (f32x4*)op);
  __builtin_nontemporal_store(o1, (f32x4*)(op + 4));
}

extern "C" void kernel_launch(void* const* d_in, const int* in_sizes, int n_in,
                              void* d_out, int out_size, void* d_ws, size_t ws_size,
                              hipStream_t stream) {
  const float* x       = (const float*)d_in[0];
  const int* ei        = (const int*)d_in[1];
  const float* ln1_g   = (const float*)d_in[2];
  const float* ln1_b   = (const float*)d_in[3];
  const float* qkv_w   = (const float*)d_in[4];
  const float* qkv_b   = (const float*)d_in[5];
  const float* out_w   = (const float*)d_in[6];
  const float* out_b   = (const float*)d_in[7];
  const float* ln2_g   = (const float*)d_in[8];
  const float* ln2_b   = (const float*)d_in[9];
  const float* ff1_w   = (const float*)d_in[10];
  const float* ff1_b   = (const float*)d_in[11];
  const float* ff2_w   = (const float*)d_in[12];
  const float* ff2_b   = (const float*)d_in[13];
  const float* gat_w   = (const float*)d_in[14];
  const float* att_src = (const float*)d_in[15];
  const float* att_dst = (const float*)d_in[16];
  const float* gat_b   = (const float*)d_in[17];
  float* out = (float*)d_out;

  short* h    = (short*)d_ws;                             // 16777216 shorts (bf16)
  float* as_g = (float*)(h + (size_t)KNODES * SEQL * DM); // 131072 floats
  float* ad_g = as_g + KNODES * SEQL;                     // 131072
  int* counts = (int*)(ad_g + KNODES * SEQL);             // 4096
  int* offs   = counts + KNODES;                          // 4097
  int* cursor = offs + KNODES + 1;                        // 4096
  int* csr    = cursor + KNODES;                          // 69632
  size_t wofs = (size_t)((char*)(csr + NETOT) - (char*)d_ws);
  wofs = (wofs + 1023) & ~(size_t)1023;
  short* wpk = (short*)((char*)d_ws + wofs);              // 416*512 shorts

  cvt_weights<<<(NFRAG * 64 + 255) / 256, 256, 0, stream>>>(qkv_w, out_w, ff1_w, ff2_w, gat_w, wpk);
  zero_counts<<<(KNODES + 255) / 256, 256, 0, stream>>>(counts);
  hist_kernel<<<(NETOT + 255) / 256, 256, 0, stream>>>(ei, counts);
  scan_kernel<<<1, 1024, 0, stream>>>(counts, offs, cursor);
  scatter_kernel<<<(NETOT + 255) / 256, 256, 0, stream>>>(ei, cursor, csr);
  temporal_kernel<<<KNODES, 512, 0, stream>>>(
      x, ln1_g, ln1_b, wpk, qkv_b, out_b, ln2_g, ln2_b,
      ff1_b, ff2_b, att_src, att_dst, h, as_g, ad_g);
  gat_aggregate<<<dim3(8, KNODES), 64, 0, stream>>>(h, as_g, ad_g, offs, csr, gat_b, out);
}